// Round 3
// baseline (1329.058 us; speedup 1.0000x reference)
//
#include <hip/hip_runtime.h>
#include <hip/hip_bf16.h>
#include <hip/hip_cooperative_groups.h>

namespace cg = cooperative_groups;

#define F_IN 1433
#define F_HID 16
#define F_OUT 7
#define KSTEPS 45  // ceil(1433/32)

typedef __bf16 bf16x8 __attribute__((ext_vector_type(8)));
typedef float f32x4 __attribute__((ext_vector_type(4)));
typedef int i32x4 __attribute__((ext_vector_type(4)));
typedef unsigned short u16;
typedef unsigned int u32;

static __device__ __forceinline__ float bf2f(u16 b) {
    return __builtin_bit_cast(float, (u32)b << 16);
}
static __device__ __forceinline__ u16 f2bf(float f) {  // RNE fp32->bf16
    u32 u = __builtin_bit_cast(u32, f);
    u32 r = u + 0x7FFFu + ((u >> 16) & 1u);
    return (u16)(r >> 16);
}
static __device__ __forceinline__ int clampN(int v, int N) {
    return ((unsigned)v < (unsigned)N) ? v : 0;
}

// Device-scope barrier among the CSR-subset blocks only (all blocks are
// co-resident under cooperative launch, so spinning cannot deadlock).
// Leader-thread fences: __syncthreads drains the block's stores to L2
// (s_waitcnt vmcnt(0) before s_barrier), then the leader's agent-scope
// release/acquire (threadfence -> buffer_wbl2/inv sc1) makes the whole
// XCD L2 visible/invalid across XCDs.
static __device__ __forceinline__ void subset_bar(int* cnt, int target) {
    __syncthreads();
    if (threadIdx.x == 0) {
        __threadfence();
        __hip_atomic_fetch_add(cnt, 1, __ATOMIC_RELEASE, __HIP_MEMORY_SCOPE_AGENT);
        while (__hip_atomic_load(cnt, __ATOMIC_ACQUIRE, __HIP_MEMORY_SCOPE_AGENT) < target) {
            __builtin_amdgcn_s_sleep(8);
        }
        __threadfence();
    }
    __syncthreads();
}

// ---------------- shared device pieces ----------------

static __device__ __forceinline__ void dev_stage_lw(const void* W1, int isbf, u16* lw, int tid) {
    const u16* W1u = (const u16*)W1;
    const float* W1f = (const float*)W1;
    for (int idx = tid; idx < KSTEPS * 512; idx += 256) {
        int j = idx & 7, lane = (idx >> 3) & 63, ks = idx >> 9;
        int quad = lane >> 4, n = lane & 15;
        int k = ks * 32 + quad * 8 + j;
        u16 w = 0;
        if (k < F_IN) w = isbf ? W1u[k * 16 + n] : f2bf(W1f[k * 16 + n]);
        lw[idx] = w;
    }
}

// GEMM1: hn = x @ W1 (UNSCALED h; dis applied per-source in agg1).
// MFMA 16x16x32 bf16; C/D: col=lane&15, row=quad*4+reg (m89-verified).
template <int ISBF>
static __device__ void dev_gemm(const u16* xu, const float* xf, const u16* lw,
                                float* __restrict__ hn, int N, int tid, int bid, int grid) {
    int wave = tid >> 6, lane = tid & 63;
    int quad = lane >> 4, m = lane & 15;
    int ntiles = (N + 63) / 64;
    int k0 = quad * 8;

    for (int tb = bid; tb < ntiles; tb += grid) {
        int base = tb * 64 + wave * 16;
        int row = base + m;
        int rowc = row < N ? row : N - 1;
        const u16* xru = xu + (size_t)rowc * F_IN;
        const float* xrf = xf + (size_t)rowc * F_IN;

        f32x4 acc = {0.f, 0.f, 0.f, 0.f};
        for (int ks = 0; ks < KSTEPS - 1; ks++) {  // k < 1408 unguarded
            u16 e[8];
            if (ISBF) {
                const u16* xp = xru + k0 + ks * 32;
#pragma unroll
                for (int j = 0; j < 8; j++) e[j] = xp[j];
            } else {
                const float* xp = xrf + k0 + ks * 32;
#pragma unroll
                for (int j = 0; j < 8; j++) e[j] = f2bf(xp[j]);
            }
            i32x4 wv = {(int)((u32)e[0] | ((u32)e[1] << 16)),
                        (int)((u32)e[2] | ((u32)e[3] << 16)),
                        (int)((u32)e[4] | ((u32)e[5] << 16)),
                        (int)((u32)e[6] | ((u32)e[7] << 16))};
            bf16x8 a = __builtin_bit_cast(bf16x8, wv);
            bf16x8 b = __builtin_bit_cast(bf16x8, *(const i32x4*)(&lw[ks * 512 + lane * 8]));
            acc = __builtin_amdgcn_mfma_f32_16x16x32_bf16(a, b, acc, 0, 0, 0);
        }
        {  // tail: k in [1408,1440) guarded
            int ks = KSTEPS - 1;
            int kb = ks * 32 + k0;
            u16 e[8];
#pragma unroll
            for (int j = 0; j < 8; j++) {
                int k = kb + j;
                e[j] = (k < F_IN) ? (ISBF ? xru[k] : f2bf(xrf[k])) : (u16)0;
            }
            i32x4 wv = {(int)((u32)e[0] | ((u32)e[1] << 16)),
                        (int)((u32)e[2] | ((u32)e[3] << 16)),
                        (int)((u32)e[4] | ((u32)e[5] << 16)),
                        (int)((u32)e[6] | ((u32)e[7] << 16))};
            bf16x8 a = __builtin_bit_cast(bf16x8, wv);
            bf16x8 b = __builtin_bit_cast(bf16x8, *(const i32x4*)(&lw[ks * 512 + lane * 8]));
            acc = __builtin_amdgcn_mfma_f32_16x16x32_bf16(a, b, acc, 0, 0, 0);
        }
#pragma unroll
        for (int r = 0; r < 4; r++) {
            int orow = base + quad * 4 + r;
            if (orow < N) hn[(size_t)orow * 16 + m] = acc[r];
        }
    }
}

// agg1 (pull over CSR, per-source dis) + relu + fused 16x7 linear2.
// 16 lanes per node; writes tn[v*8+0..6] = (y1 @ W2)[c] * dis[v], col 7 = 0.
static __device__ void dev_agg1(const float* __restrict__ hn, const int* __restrict__ csr,
                                const int* __restrict__ rowoff, const int* __restrict__ deg,
                                const float* __restrict__ dis, const void* __restrict__ b1,
                                const void* __restrict__ W2, int isbf,
                                float* __restrict__ tn, int N, int bid, int grid, int tid) {
    int lane = tid & 63;
    int c = tid & 15, g = tid >> 4;
    float bc = isbf ? bf2f(((const u16*)b1)[c]) : ((const float*)b1)[c];
    float w2c[16];
#pragma unroll
    for (int k = 0; k < 16; k++) {
        float w = 0.f;
        if (c < 7) w = isbf ? bf2f(((const u16*)W2)[k * 7 + c]) : ((const float*)W2)[k * 7 + c];
        w2c[k] = w;
    }
    for (int v = bid * 16 + g; v < N; v += grid * 16) {
        float dv = dis[v];
        float acc = hn[(size_t)v * 16 + c] * dv;  // self-loop msg: h[v]*dis[v]
        int s0 = rowoff[v], d = deg[v];
        const int* cp = csr + s0;
        float a1 = 0.f, a2 = 0.f, a3 = 0.f;
        int i = 0;
        for (; i + 4 <= d; i += 4) {  // 4 independent gather chains
            int sA = clampN(cp[i], N), sB = clampN(cp[i + 1], N);
            int sC = clampN(cp[i + 2], N), sD = clampN(cp[i + 3], N);
            acc += hn[(size_t)sA * 16 + c] * dis[sA];
            a1 += hn[(size_t)sB * 16 + c] * dis[sB];
            a2 += hn[(size_t)sC * 16 + c] * dis[sC];
            a3 += hn[(size_t)sD * 16 + c] * dis[sD];
        }
        for (; i < d; i++) {
            int s = clampN(cp[i], N);
            acc += hn[(size_t)s * 16 + c] * dis[s];
        }
        acc += (a1 + a2) + a3;
        float y = fmaxf(acc * dv + bc, 0.f);  // y1[v][c]
        float s = 0.f;
#pragma unroll
        for (int k = 0; k < 16; k++) s += __shfl(y, (lane & 48) + k, 64) * w2c[k];
        if (c < 8) tn[(size_t)v * 8 + c] = (c < 7) ? s * dv : 0.f;
    }
}

// agg2 (pull over CSR; tn pre-scaled by source dis) + bias + log_softmax.
static __device__ void dev_agg2(const float* __restrict__ tn, const int* __restrict__ csr,
                                const int* __restrict__ rowoff, const int* __restrict__ deg,
                                const float* __restrict__ dis, const void* __restrict__ b2,
                                int isbf, void* __restrict__ out, int N, int bid, int grid,
                                int tid) {
    int c = tid & 7, g = tid >> 3;
    float bc = 0.f;
    if (c < 7) bc = isbf ? bf2f(((const u16*)b2)[c]) : ((const float*)b2)[c];
    for (int v = bid * 32 + g; v < N; v += grid * 32) {
        float acc = tn[(size_t)v * 8 + c];  // self-loop; col 7 = 0 pad
        int s0 = rowoff[v], d = deg[v];
        const int* cp = csr + s0;
        float a1 = 0.f, a2 = 0.f, a3 = 0.f;
        int i = 0;
        for (; i + 4 <= d; i += 4) {
            int sA = clampN(cp[i], N), sB = clampN(cp[i + 1], N);
            int sC = clampN(cp[i + 2], N), sD = clampN(cp[i + 3], N);
            acc += tn[(size_t)sA * 8 + c];
            a1 += tn[(size_t)sB * 8 + c];
            a2 += tn[(size_t)sC * 8 + c];
            a3 += tn[(size_t)sD * 8 + c];
        }
        for (; i < d; i++) acc += tn[(size_t)clampN(cp[i], N) * 8 + c];
        acc += (a1 + a2) + a3;

        float z = (c < 7) ? (acc * dis[v] + bc) : -1e30f;
        float mx = z;
#pragma unroll
        for (int o = 1; o < 8; o <<= 1) mx = fmaxf(mx, __shfl_xor(mx, o, 8));
        float ex = (c < 7) ? expf(z - mx) : 0.f;
        float sm = ex;
#pragma unroll
        for (int o = 1; o < 8; o <<= 1) sm += __shfl_xor(sm, o, 8);
        sm = fmaxf(sm, 1e-30f);
        if (c < 7) {
            float res = z - mx - logf(sm);
            if (isbf)
                ((u16*)out)[(size_t)v * 7 + c] = f2bf(res);
            else
                ((float*)out)[(size_t)v * 7 + c] = res;
        }
    }
}

// ---------------- cooperative megakernel ----------------

struct MegaArgs {
    const void* x;
    const int* ei;
    const void* W1;
    const void* b1;
    const void* W2;
    const void* b2;
    int* flags;
    int* cnt;
    int* deg;
    int* rowoff;
    int* fill;
    int* bsum;
    float* dis;
    int* csr;
    float* hn;
    float* tn;
    void* out;
    int N;
    int E;
};

__global__ __launch_bounds__(256) void k_mega(MegaArgs a) {
    cg::grid_group gg = cg::this_grid();
    int tid = threadIdx.x;
    int b = blockIdx.x;
    int G = gridDim.x;

    __shared__ int sflags[2];
    __shared__ __align__(16) u16 lw[KSTEPS * 512];
    __shared__ int sscan[256];
    __shared__ int swsum[4];

    // ---- P0: zero deg + barrier counter; detect dtypes (block 0) ----
    for (int i = b * 256 + tid; i < a.N; i += G * 256) a.deg[i] = 0;
    if (b == 0) {
        if (tid == 0) a.cnt[0] = 0;
        if (tid < 64) {
            u16 v = ((const u16*)a.x)[tid];
            int e = (v >> 7) & 0xFF;
            unsigned long long mb = __ballot(e >= 100 && e <= 140);
            unsigned long long mz = __ballot(a.ei[2 * tid + 1] == 0);
            if (tid == 0) {
                a.flags[0] = (__popcll(mb) >= 56) ? 1 : 0;
                a.flags[1] = (__popcll(mz) >= 48) ? 1 : 0;
            }
        }
    }
    gg.sync();

    if (tid == 0) {
        sflags[0] = a.flags[0];
        sflags[1] = a.flags[1];
    }
    __syncthreads();
    int isbf = sflags[0], sh = sflags[1];

    // ---- P1 (overlapped): blocks [0,G2) GEMM, blocks [G2,G) CSR build ----
    int G2 = G >> 1;
    int nb = G - G2;
    if (b < G2) {
        dev_stage_lw(a.W1, isbf, lw, tid);
        __syncthreads();
        if (isbf)
            dev_gemm<1>((const u16*)a.x, (const float*)a.x, lw, a.hn, a.N, tid, b, G2);
        else
            dev_gemm<0>((const u16*)a.x, (const float*)a.x, lw, a.hn, a.N, tid, b, G2);
    } else {
        int lb = b - G2;
        // deg
        for (int i = lb * 256 + tid; i < a.E; i += nb * 256) {
            int d = a.ei[(size_t)(a.E + i) << sh];
            atomicAdd(&a.deg[clampN(d, a.N)], 1);
        }
        subset_bar(a.cnt, nb * 1);
        // scan-a: per-block chunk scan -> bsum
        int chunk = (a.N + nb - 1) / nb;
        int q = (chunk + 255) / 256;
        int base = lb * chunk;
        int nend = base + chunk;
        if (nend > a.N) nend = a.N;
        int tot = 0;
        for (int jj = 0; jj < q; jj++) {
            int node = base + tid * q + jj;
            if (node < nend) tot += a.deg[node];
        }
        sscan[tid] = tot;
        __syncthreads();
        for (int o = 1; o < 256; o <<= 1) {
            int xv = (tid >= o) ? sscan[tid - o] : 0;
            __syncthreads();
            sscan[tid] += xv;
            __syncthreads();
        }
        int incl = sscan[tid];
        if (tid == 255) a.bsum[lb] = incl;
        __syncthreads();
        sscan[tid] = incl - tot;  // thread's exclusive base within chunk (LDS persists)
        subset_bar(a.cnt, nb * 2);
        // scan-b: block offset = sum of preceding bsum; write rowoff/fill/dis
        int part = 0;
        for (int j = tid; j < lb; j += 256) part += a.bsum[j];
        for (int o = 32; o > 0; o >>= 1) part += __shfl_down(part, o, 64);
        if ((tid & 63) == 0) swsum[tid >> 6] = part;
        __syncthreads();
        int off = swsum[0] + swsum[1] + swsum[2] + swsum[3];
        int run = off + sscan[tid];
        for (int jj = 0; jj < q; jj++) {
            int node = base + tid * q + jj;
            if (node < nend) {
                int dn = a.deg[node];
                a.rowoff[node] = run;
                a.fill[node] = run;
                a.dis[node] = rsqrtf((float)(dn + 1));
                run += dn;
            }
        }
        subset_bar(a.cnt, nb * 3);
        // fill
        for (int i = lb * 256 + tid; i < a.E; i += nb * 256) {
            int d = a.ei[(size_t)(a.E + i) << sh];
            int s = a.ei[(size_t)i << sh];
            int slot = atomicAdd(&a.fill[clampN(d, a.N)], 1);
            if (slot >= 0 && slot < a.E) a.csr[slot] = clampN(s, a.N);
        }
    }
    gg.sync();

    // ---- P2: agg1 + relu + fused linear2 ----
    dev_agg1(a.hn, a.csr, a.rowoff, a.deg, a.dis, a.b1, a.W2, isbf, a.tn, a.N, b, G, tid);
    gg.sync();

    // ---- P3: agg2 + log_softmax ----
    dev_agg2(a.tn, a.csr, a.rowoff, a.deg, a.dis, a.b2, isbf, a.out, a.N, b, G, tid);
}

// ---------------- fallback multi-kernel path (if coop launch unavailable) ----------------

__global__ __launch_bounds__(256) void k_init(const u16* __restrict__ xu,
                                              const int* __restrict__ ei,
                                              int* __restrict__ flags,
                                              int* __restrict__ deg, int N) {
    int i = blockIdx.x * 256 + threadIdx.x;
    if (i < N) deg[i] = 0;
    if (blockIdx.x == 0 && threadIdx.x < 64) {
        int t = threadIdx.x;
        u16 v = xu[t];
        int e = (v >> 7) & 0xFF;
        unsigned long long mb = __ballot(e >= 100 && e <= 140);
        unsigned long long mz = __ballot(ei[2 * t + 1] == 0);
        if (t == 0) {
            flags[0] = (__popcll(mb) >= 56) ? 1 : 0;
            flags[1] = (__popcll(mz) >= 48) ? 1 : 0;
        }
    }
}

__global__ __launch_bounds__(256) void k_deg(const int* __restrict__ ei,
                                             const int* __restrict__ flags,
                                             int* __restrict__ deg, int E, int N) {
    int sh = flags[1];
    int i = blockIdx.x * 256 + threadIdx.x;
    if (i < E) {
        int d = ei[(size_t)(E + i) << sh];
        atomicAdd(&deg[clampN(d, N)], 1);
    }
}

__global__ __launch_bounds__(256) void k_scan1(const int* __restrict__ deg,
                                               int* __restrict__ rowoff,
                                               int* __restrict__ bsum, int N) {
    __shared__ int s[256];
    int t = threadIdx.x, i = blockIdx.x * 256 + t;
    int v = (i < N) ? deg[i] : 0;
    s[t] = v;
    __syncthreads();
    for (int o = 1; o < 256; o <<= 1) {
        int x = 0;
        if (t >= o) x = s[t - o];
        __syncthreads();
        s[t] += x;
        __syncthreads();
    }
    if (i < N) rowoff[i] = s[t] - v;
    if (t == 255) bsum[blockIdx.x] = s[255];
}

__global__ __launch_bounds__(1024) void k_scan2(const int* __restrict__ bsum,
                                                int* __restrict__ bscan, int NB) {
    __shared__ int s[1024];
    int t = threadIdx.x;
    int v = (t < NB) ? bsum[t] : 0;
    s[t] = v;
    __syncthreads();
    for (int o = 1; o < 1024; o <<= 1) {
        int x = 0;
        if (t >= o) x = s[t - o];
        __syncthreads();
        s[t] += x;
        __syncthreads();
    }
    if (t < NB) bscan[t] = s[t] - v;
}

__global__ __launch_bounds__(256) void k_scan3(const int* __restrict__ deg,
                                               int* __restrict__ rowoff,
                                               const int* __restrict__ bscan,
                                               int* __restrict__ fill,
                                               float* __restrict__ dis, int N) {
    int i = blockIdx.x * 256 + threadIdx.x;
    if (i >= N) return;
    int ro = rowoff[i] + bscan[blockIdx.x];
    rowoff[i] = ro;
    fill[i] = ro;
    dis[i] = rsqrtf((float)(deg[i] + 1));
}

__global__ __launch_bounds__(256) void k_fill(const int* __restrict__ ei,
                                              const int* __restrict__ flags,
                                              int* __restrict__ fill,
                                              int* __restrict__ csr, int E, int N) {
    int sh = flags[1];
    int i = blockIdx.x * 256 + threadIdx.x;
    if (i < E) {
        int d = ei[(size_t)(E + i) << sh];
        int s = ei[(size_t)i << sh];
        int slot = atomicAdd(&fill[clampN(d, N)], 1);
        if (slot >= 0 && slot < E) csr[slot] = clampN(s, N);
    }
}

__global__ __launch_bounds__(256) void k_gemm1(const void* __restrict__ x,
                                               const void* __restrict__ W1,
                                               const int* __restrict__ flags,
                                               float* __restrict__ hn, int N) {
    __shared__ __align__(16) u16 lw[KSTEPS * 512];
    int tid = threadIdx.x;
    int isbf = flags[0];
    dev_stage_lw(W1, isbf, lw, tid);
    __syncthreads();
    if (isbf)
        dev_gemm<1>((const u16*)x, (const float*)x, lw, hn, N, tid, blockIdx.x, gridDim.x);
    else
        dev_gemm<0>((const u16*)x, (const float*)x, lw, hn, N, tid, blockIdx.x, gridDim.x);
}

__global__ __launch_bounds__(256) void k_agg1(const float* __restrict__ hn,
                                              const int* __restrict__ csr,
                                              const int* __restrict__ rowoff,
                                              const int* __restrict__ deg,
                                              const float* __restrict__ dis,
                                              const void* __restrict__ b1,
                                              const void* __restrict__ W2,
                                              const int* __restrict__ flags,
                                              float* __restrict__ tn, int N) {
    dev_agg1(hn, csr, rowoff, deg, dis, b1, W2, flags[0], tn, N, blockIdx.x, gridDim.x,
             threadIdx.x);
}

__global__ __launch_bounds__(256) void k_agg2(const float* __restrict__ tn,
                                              const int* __restrict__ csr,
                                              const int* __restrict__ rowoff,
                                              const int* __restrict__ deg,
                                              const float* __restrict__ dis,
                                              const void* __restrict__ b2,
                                              const int* __restrict__ flags,
                                              void* __restrict__ out, int N) {
    dev_agg2(tn, csr, rowoff, deg, dis, b2, flags[0], out, N, blockIdx.x, gridDim.x,
             threadIdx.x);
}

// ---------------- launch ----------------

extern "C" void kernel_launch(void* const* d_in, const int* in_sizes, int n_in,
                              void* d_out, int out_size, void* d_ws, size_t ws_size,
                              hipStream_t stream) {
    const void* x = d_in[0];
    const int* ei = (const int*)d_in[1];
    const void* W1 = d_in[2];
    const void* b1 = d_in[3];
    const void* W2 = d_in[4];
    const void* b2 = d_in[5];

    int N = in_sizes[0] / F_IN;
    int E = in_sizes[1] / 2;

    char* p = (char*)d_ws;
    size_t off = 0;
    auto alloc = [&](size_t bytes) -> void* {
        off = (off + 255) & ~(size_t)255;
        void* r = p + off;
        off += bytes;
        return r;
    };
    int* flags = (int*)alloc(256);
    int* cnt = (int*)alloc(256);
    int* deg = (int*)alloc((size_t)N * 4);
    int* rowoff = (int*)alloc((size_t)N * 4);
    int* fill = (int*)alloc((size_t)N * 4);
    int* bsum = (int*)alloc(1024 * 4);
    int* bscan = (int*)alloc(1024 * 4);
    float* dis = (float*)alloc((size_t)N * 4);
    int* csr = (int*)alloc((size_t)E * 4);
    float* hn = (float*)alloc((size_t)N * 16 * 4);
    float* tn = (float*)alloc((size_t)N * 8 * 4);
    (void)ws_size;
    (void)n_in;
    (void)out_size;

    // --- try the cooperative megakernel ---
    static int s_mb = -1;
    if (s_mb < 0) {
        int mb = 0;
        if (hipOccupancyMaxActiveBlocksPerMultiprocessor(
                &mb, reinterpret_cast<const void*>(&k_mega), 256, 0) != hipSuccess ||
            mb < 1)
            mb = 0;
        s_mb = mb;
    }
    int grid = s_mb * 256;  // 256 CUs on MI355X
    if (grid > 1024) grid = 1024;

    bool ok = false;
    if (grid >= 8) {
        MegaArgs ha = {x,    ei,  W1,   b1,  W2, b2,  flags, cnt, deg,
                       rowoff, fill, bsum, dis, csr, hn, tn,  d_out, N,   E};
        void* params[] = {&ha};
        ok = (hipLaunchCooperativeKernel(reinterpret_cast<void*>(&k_mega), dim3(grid),
                                         dim3(256), params, 0, stream) == hipSuccess);
        if (!ok) (void)hipGetLastError();  // clear sticky error before fallback
    }

    if (!ok) {
        int gE = (E + 255) / 256;
        int gN = (N + 255) / 256;
        k_init<<<gN, 256, 0, stream>>>((const u16*)x, ei, flags, deg, N);
        k_deg<<<gE, 256, 0, stream>>>(ei, flags, deg, E, N);
        k_scan1<<<gN, 256, 0, stream>>>(deg, rowoff, bsum, N);
        k_scan2<<<1, 1024, 0, stream>>>(bsum, bscan, gN);
        k_scan3<<<gN, 256, 0, stream>>>(deg, rowoff, bscan, fill, dis, N);
        k_fill<<<gE, 256, 0, stream>>>(ei, flags, fill, csr, E, N);
        int ntiles = (N + 63) / 64;
        int gg = ntiles < 768 ? ntiles : 768;
        k_gemm1<<<gg, 256, 0, stream>>>(x, W1, flags, hn, N);
        k_agg1<<<(N + 15) / 16, 256, 0, stream>>>(hn, csr, rowoff, deg, dis, b1, W2, flags, tn, N);
        k_agg2<<<(N + 31) / 32, 256, 0, stream>>>(tn, csr, rowoff, deg, dis, b2, flags, d_out, N);
    }
}